// Round 8
// baseline (315.023 us; speedup 1.0000x reference)
//
#include <hip/hip_runtime.h>
#include <hip/hip_bf16.h>

#define BB 2
#define NN 2048
#define DD 128
#define HH 8
#define OUTD 256
#define SCALE 0.022097086912079612f  // 1/sqrt(2048)

typedef __bf16 bf16x8 __attribute__((ext_vector_type(8)));
typedef float f32x4 __attribute__((ext_vector_type(4)));
typedef _Float16 f16x8 __attribute__((ext_vector_type(8)));

__device__ __forceinline__ unsigned short f2bf(float f) {
    union { float f; unsigned int u; } v; v.f = f;
    unsigned int r = (v.u + 0x7FFFu + ((v.u >> 16) & 1u)) >> 16;
    return (unsigned short)r;
}
__device__ __forceinline__ float bf2f(unsigned short s) {
    union { unsigned int u; float f; } v; v.u = ((unsigned int)s) << 16;
    return v.f;
}
// async global->LDS, 16 B per lane; lds dst = wave-uniform base + lane*16
__device__ __forceinline__ void gl_lds16(const unsigned short* g, unsigned short* l) {
    __builtin_amdgcn_global_load_lds(
        (const __attribute__((address_space(1))) unsigned int*)g,
        (__attribute__((address_space(3))) unsigned int*)l,
        16, 0, 0);
}

// ---------------- prep: bf16 casts + weight transposes ----------------
__global__ void prep_kernel(const float* __restrict__ X,
                            const float* __restrict__ Wq,
                            const float* __restrict__ Wk,
                            const float* __restrict__ Wv,
                            const float* __restrict__ Wout,
                            unsigned short* __restrict__ Xb,     // [B][N][D]
                            unsigned short* __restrict__ WT,     // [3][H][e][d]
                            unsigned short* __restrict__ WoutT)  // [OUT][H*D]
{
    const int NX  = BB * NN * DD;        // 524288
    const int NW  = 3 * HH * DD * DD;    // 393216
    const int NWO = (HH * DD) * OUTD;    // 262144
    int idx = blockIdx.x * blockDim.x + threadIdx.x;
    if (idx < NX) {
        Xb[idx] = f2bf(X[idx]);
    } else if (idx < NX + NW) {
        int i = idx - NX;
        int mat = i / (HH * DD * DD);
        int r   = i % (HH * DD * DD);
        int h = r / (DD * DD);
        int j = r % (DD * DD);
        int e = j / DD;
        int d = j % DD;
        const float* Wm = (mat == 0) ? Wq : ((mat == 1) ? Wk : Wv);
        WT[i] = f2bf(Wm[h * DD * DD + d * DD + e]);
    } else if (idx < NX + NW + NWO) {
        int i = idx - NX - NW;
        int o = i / (HH * DD);
        int k = i % (HH * DD);
        WoutT[i] = f2bf(Wout[k * OUTD + o]);
    }
}

// ---------------- adjsum: nodeadj.sum(-1) -> bf16, vectorized ----------------
// v2: 8 outputs/thread -> 8x contiguous float4 reads (128 B/lane) and one
// uint4 store (16 B/lane = 1 KB/wave, vs the old 2 B/lane scalar store that
// capped a wave's store at 128 B). Grid-stride, 2048 blocks (G11/G13).
// Per-output math identical: f2bf((x+y)+(z+w)).
__global__ __launch_bounds__(256) void adjsum_kernel(
    const float4* __restrict__ adj, unsigned short* __restrict__ s)
{
    const int total = BB * NN * NN / 8;   // 1,048,576 groups of 8 outputs
    for (int c = blockIdx.x * blockDim.x + threadIdx.x; c < total;
         c += gridDim.x * blockDim.x) {
        unsigned short u[8];
        #pragma unroll
        for (int i = 0; i < 8; ++i) {
            float4 a = adj[c * 8 + i];
            u[i] = f2bf((a.x + a.y) + (a.z + a.w));
        }
        *(uint4*)(s + (size_t)c * 8) = *(const uint4*)u;
    }
}

// ---------------- projections q/k/v ----------------
// grid (N/64, B*H, 3); block 256. mat: 0=Q, 1=K, 2=V(transposed output via LDS)
__global__ __launch_bounds__(256) void proj_kernel(
    const unsigned short* __restrict__ Xb,
    const unsigned short* __restrict__ WT,
    const float* __restrict__ bq, const float* __restrict__ bk, const float* __restrict__ bv,
    unsigned short* __restrict__ Qo, unsigned short* __restrict__ Ko,
    unsigned short* __restrict__ Vt)
{
    const int mat = blockIdx.z;
    const int bh  = blockIdx.y;
    const int b = bh >> 3, h = bh & 7;
    const int n0 = blockIdx.x * 64;
    const int tid = threadIdx.x;
    const int lane = tid & 63, wv = tid >> 6;
    const int m = lane & 15, quad = lane >> 4;

    __shared__ unsigned short Wlds[128 * 136];  // [e][d], pad 136; reused for V transpose

    const unsigned short* Wg = WT + ((size_t)mat * HH + h) * (DD * DD);
    #pragma unroll
    for (int i = tid; i < 128 * 16; i += 256) {
        int r = i >> 4, c = i & 15;
        *(uint4*)&Wlds[r * 136 + c * 8] = *(const uint4*)(Wg + r * 128 + c * 8);
    }

    const int row = n0 + wv * 16 + m;
    const unsigned short* Xr = Xb + ((size_t)b * NN + row) * DD;
    bf16x8 af[4];
    #pragma unroll
    for (int kc = 0; kc < 4; ++kc)
        af[kc] = *(const bf16x8*)(Xr + kc * 32 + quad * 8);

    __syncthreads();

    f32x4 acc[8];
    #pragma unroll
    for (int et = 0; et < 8; ++et) acc[et] = (f32x4){0.f, 0.f, 0.f, 0.f};

    #pragma unroll
    for (int kc = 0; kc < 4; ++kc) {
        #pragma unroll
        for (int et = 0; et < 8; ++et) {
            bf16x8 bfrg = *(const bf16x8*)&Wlds[(et * 16 + m) * 136 + kc * 32 + quad * 8];
            acc[et] = __builtin_amdgcn_mfma_f32_16x16x32_bf16(af[kc], bfrg, acc[et], 0, 0, 0);
        }
    }

    const float* bias = (mat == 0) ? bq : ((mat == 1) ? bk : bv);
    if (mat != 2) {
        #pragma unroll
        for (int et = 0; et < 8; ++et) {
            int e = et * 16 + m;
            float bb = bias[h * DD + e];
            #pragma unroll
            for (int reg = 0; reg < 4; ++reg) {
                int r = n0 + wv * 16 + quad * 4 + reg;
                unsigned short v16 = f2bf(acc[et][reg] + bb);
                if (mat == 0) Qo[((size_t)bh * NN + r) * DD + e] = v16;
                else          Ko[((size_t)bh * NN + r) * DD + e] = v16;
            }
        }
    } else {
        // V: transpose through LDS -> coalesced uint4 stores to Vt[bh][e][n]
        __syncthreads();  // everyone done with Wlds MFMA reads
        #pragma unroll
        for (int et = 0; et < 8; ++et) {
            int e = et * 16 + m;
            float bb = bias[h * DD + e];
            #pragma unroll
            for (int reg = 0; reg < 4; ++reg)
                Wlds[(wv * 16 + quad * 4 + reg) * 136 + e] = f2bf(acc[et][reg] + bb);
        }
        __syncthreads();
        const int e = tid >> 1, nh = tid & 1;
        #pragma unroll
        for (int j = 0; j < 4; ++j) {
            unsigned short tmp[8];
            #pragma unroll
            for (int kk = 0; kk < 8; ++kk)
                tmp[kk] = Wlds[(nh * 32 + j * 8 + kk) * 136 + e];
            *(uint4*)(Vt + ((size_t)bh * DD + e) * NN + n0 + nh * 32 + j * 8) = *(uint4*)tmp;
        }
    }
}

// ---------------- flash attention, split-K x2, async LDS staging ----------------
// R0-verbatim schedule: 16 q-rows/wave, 4 waves/block, 4 blocks/CU, TK=32,
// 2-buffer K/V via global_load_lds, __syncthreads per kt. All R1-R5 schedule
// variants (32-row waves, vectorized adj, 3-buffer counted vmcnt) measured
// slower. grid (128, 8): x = ((b*32 + qt)*2 + ks), y = h.
__global__ __launch_bounds__(256, 4) void attn_kernel(
    const unsigned short* __restrict__ Q,
    const unsigned short* __restrict__ K,
    const unsigned short* __restrict__ Vt,
    const unsigned short* __restrict__ adjs,   // bf16 [B][N][N]
    _Float16* __restrict__ Opart,              // [2][BH][N][D] fp16 partials
    float* __restrict__ Lpart)                 // [2][BH][N] fp32 partial row-sums
{
    const int x = blockIdx.x;
    const int h = blockIdx.y;
    const int ks = x & 1, qt = (x >> 1) & 31, b = x >> 6;
    const int bh = b * HH + h;
    const int q0 = qt * 64;
    const int kstart = ks * 1024;
    const int tid = threadIdx.x;
    const int lane = tid & 63, wv = tid >> 6;
    const int m = lane & 15, quad = lane >> 4;

    __shared__ unsigned short Kb[2][32 * 128];   // [key][d] swizzled, 8 KB each
    __shared__ unsigned short Vb[2][128 * 32];   // [d][key] swizzled, 8 KB each
    __shared__ unsigned short Plds[4][16 * 40];  // per-wave P, pad 40 -> 5 KB
    // total 37.9 KB -> 4 blocks/CU

    const unsigned short* Kbase = K + (size_t)bh * NN * DD;
    const unsigned short* Vbase = Vt + (size_t)bh * DD * NN;

    // Q fragments (register-resident for whole kernel)
    const int qrow = q0 + wv * 16 + m;
    const unsigned short* Qr = Q + ((size_t)bh * NN + qrow) * DD;
    bf16x8 qf[4];
    #pragma unroll
    for (int kc = 0; kc < 4; ++kc)
        qf[kc] = *(const bf16x8*)(Qr + kc * 32 + quad * 8);

    f32x4 o[8];
    #pragma unroll
    for (int dt = 0; dt < 8; ++dt) o[dt] = (f32x4){0.f, 0.f, 0.f, 0.f};
    float li[4] = {0.f, 0.f, 0.f, 0.f};

    const unsigned short* Abase = adjs + ((size_t)b * NN + q0 + wv * 16 + quad * 4) * NN;

    // staging lane decomposition
    const int kr4 = lane >> 4, kc16 = lane & 15;  // K: 4 rows x 16 chunks / instr
    const int vr16 = lane >> 2, vc4 = lane & 3;   // V: 16 rows x 4 chunks / instr

    // each wave stages K-instrs {2w,2w+1} (rows 8w..8w+7) and V-instrs {2w,2w+1} (d rows 32w..32w+31)
    #define STAGE(buf, kbase_)                                                              \
        {                                                                                   \
            _Pragma("unroll")                                                               \
            for (int j2 = 0; j2 < 2; ++j2) {                                                \
                const int j = wv * 2 + j2;                                                  \
                const int krow = j * 4 + kr4;                                               \
                gl_lds16(Kbase + (size_t)((kbase_) + krow) * DD + ((kc16 ^ (krow & 15)) * 8),\
                         &Kb[buf][j * 512]);                                                \
                const int vrow = j * 16 + vr16;                                             \
                gl_lds16(Vbase + (size_t)vrow * NN + (kbase_) + ((vc4 ^ ((vr16 >> 1) & 3)) * 8),\
                         &Vb[buf][j * 512]);                                                \
            }                                                                               \
        }

    STAGE(0, kstart);
    __syncthreads();   // vmcnt drain -> tile 0 ready

    for (int kt = 0; kt < 32; ++kt) {
        const int cb = kt & 1, nb = cb ^ 1;
        const int k0 = kstart + kt * 32;

        // adj (bf16) for current tile, per-lane scalar loads (consumed after QK)
        float areg[2][4];
        #pragma unroll
        for (int nt = 0; nt < 2; ++nt)
            #pragma unroll
            for (int reg = 0; reg < 4; ++reg)
                areg[nt][reg] = bf2f(Abase[(size_t)reg * NN + k0 + nt * 16 + m]) * SCALE;

        // async-stage next tile (no wait here; barrier at loop end drains)
        if (kt + 1 < 32) STAGE(nb, k0 + 32);

        // QK^T : 8 MFMA
        f32x4 s[2];
        s[0] = (f32x4){0.f, 0.f, 0.f, 0.f};
        s[1] = (f32x4){0.f, 0.f, 0.f, 0.f};
        #pragma unroll
        for (int kc = 0; kc < 4; ++kc) {
            #pragma unroll
            for (int nt = 0; nt < 2; ++nt) {
                bf16x8 kf = *(const bf16x8*)&Kb[cb][(nt * 16 + m) * 128 + (((kc * 4 + quad) ^ m) * 8)];
                s[nt] = __builtin_amdgcn_mfma_f32_16x16x32_bf16(qf[kc], kf, s[nt], 0, 0, 0);
            }
        }

        // p = exp(s*scale*adj)  (no max subtraction: |s*a| < ~1)
        #pragma unroll
        for (int nt = 0; nt < 2; ++nt) {
            #pragma unroll
            for (int reg = 0; reg < 4; ++reg) {
                float p = __expf(s[nt][reg] * areg[nt][reg]);
                li[reg] += p;
                Plds[wv][(quad * 4 + reg) * 40 + nt * 16 + m] = f2bf(p);
            }
        }

        // P x V : 8 MFMA (K=32 covers full tile)
        bf16x8 pf = *(const bf16x8*)&Plds[wv][m * 40 + quad * 8];
        #pragma unroll
        for (int dt = 0; dt < 8; ++dt) {
            bf16x8 vf = *(const bf16x8*)&Vb[cb][(dt * 16 + m) * 32 + ((quad ^ ((m >> 1) & 3)) * 8)];
            o[dt] = __builtin_amdgcn_mfma_f32_16x16x32_bf16(pf, vf, o[dt], 0, 0, 0);
        }

        __syncthreads();  // readers done with cb; stage(nb) drained (vmcnt0 at barrier)
    }
    #undef STAGE

    // partial row-sums: reduce li across the 16 lanes of each row group
    #pragma unroll
    for (int reg = 0; reg < 4; ++reg) {
        float t = li[reg];
        t += __shfl_xor(t, 1);
        t += __shfl_xor(t, 2);
        t += __shfl_xor(t, 4);
        t += __shfl_xor(t, 8);
        li[reg] = t;
    }
    const int rbase = q0 + wv * 16 + quad * 4;
    if (m == 0) {
        #pragma unroll
        for (int reg = 0; reg < 4; ++reg)
            Lpart[((size_t)ks * (BB * HH) + bh) * NN + rbase + reg] = li[reg];
    }
    // unnormalized partial O in fp16
    #pragma unroll
    for (int reg = 0; reg < 4; ++reg) {
        const size_t obase = (((size_t)ks * (BB * HH) + bh) * NN + rbase + reg) * DD;
        #pragma unroll
        for (int dt = 0; dt < 8; ++dt)
            Opart[obase + dt * 16 + m] = (_Float16)o[dt][reg];
    }
}

// ---------------- fused combine + output projection ----------------
// v2: row-split tiles for 2x TLP. grid (128, 4) = 512 blocks = 2/CU (was
// 256 = 1/CU, serial 8-phase k-loop fully latency-exposed). Tile 32 rows x
// 64 cols; wave wv -> row half (wv&1), col half (wv>>1): 16 rows x 32 cols
// each, 8 MFMA/kc. Opart traffic unchanged (rows split, not cols); W re-read
// doubles but W is 0.5 MB, L2-resident. A-fragments computed on the fly from
// split-K partials: a = f2bf((o0+o1)*l) — bit-identical to combine_kernel.
__global__ __launch_bounds__(256) void out_kernel(
    const _Float16* __restrict__ Op,        // [2][BH][N][D] fp16 partials
    const float* __restrict__ Lp,           // [2][BH][N]
    const unsigned short* __restrict__ WoutT,   // [OUT][HD]
    const float* __restrict__ bout,
    float* __restrict__ out)
{
    const int SPLIT_OFF = BB * HH * NN * DD;   // 4,194,304 (f16 elems)
    const int m0 = blockIdx.x * 32;
    const int c0 = blockIdx.y * 64;
    const int tid = threadIdx.x;
    const int lane = tid & 63, wv = tid >> 6;
    const int m = lane & 15, quad = lane >> 4;
    const int rh = wv & 1, ch = wv >> 1;   // row half / col half

    __shared__ unsigned short Wlds[64 * 136];

    f32x4 acc[2];
    acc[0] = (f32x4){0.f, 0.f, 0.f, 0.f};
    acc[1] = (f32x4){0.f, 0.f, 0.f, 0.f};

    const int r = m0 + rh * 16 + m;        // A-row this lane reads
    const int b = r >> 11, n = r & (NN - 1);

    for (int kc = 0; kc < 8; ++kc) {       // kc == head h
        #pragma unroll
        for (int i = tid; i < 64 * 16; i += 256) {
            int rr = i >> 4, c = i & 15;
            *(uint4*)&Wlds[rr * 136 + c * 8] =
                *(const uint4*)(WoutT + (size_t)(c0 + rr) * (HH * DD) + kc * 128 + c * 8);
        }
        __syncthreads();

        const int bh = b * HH + kc;
        const float l = 1.0f / (Lp[bh * NN + n] + Lp[BB * HH * NN + bh * NN + n]);
        const _Float16* pa = Op + ((size_t)bh * NN + n) * DD;

        #pragma unroll
        for (int j = 0; j < 4; ++j) {
            f16x8 va = *(const f16x8*)(pa + j * 32 + quad * 8);
            f16x8 vc = *(const f16x8*)(pa + SPLIT_OFF + j * 32 + quad * 8);
            unsigned short uu[8];
            #pragma unroll
            for (int i = 0; i < 8; ++i)
                uu[i] = f2bf(((float)va[i] + (float)vc[i]) * l);
            bf16x8 afr = *(const bf16x8*)uu;
            #pragma unroll
            for (int nt = 0; nt < 2; ++nt) {
                bf16x8 bfr = *(const bf16x8*)&Wlds[(ch * 32 + nt * 16 + m) * 136 + j * 32 + quad * 8];
                acc[nt] = __builtin_amdgcn_mfma_f32_16x16x32_bf16(afr, bfr, acc[nt], 0, 0, 0);
            }
        }
        __syncthreads();
    }

    #pragma unroll
    for (int nt = 0; nt < 2; ++nt) {
        int oc = c0 + ch * 32 + nt * 16 + m;
        float bb = bout[oc];
        #pragma unroll
        for (int reg = 0; reg < 4; ++reg) {
            int rr = m0 + rh * 16 + quad * 4 + reg;
            out[(size_t)rr * OUTD + oc] = acc[nt][reg] + bb;
        }
    }
}

extern "C" void kernel_launch(void* const* d_in, const int* in_sizes, int n_in,
                              void* d_out, int out_size, void* d_ws, size_t ws_size,
                              hipStream_t stream)
{
    const float* X    = (const float*)d_in[0];
    const float* adj  = (const float*)d_in[1];
    const float* Wq   = (const float*)d_in[2];
    const float* bq   = (const float*)d_in[3];
    const float* Wk   = (const float*)d_in[4];
    const float* bk   = (const float*)d_in[5];
    const float* Wv   = (const float*)d_in[6];
    const float* bv   = (const float*)d_in[7];
    const float* Wout = (const float*)d_in[8];
    const float* bout = (const float*)d_in[9];
    float* out = (float*)d_out;

    char* ws = (char*)d_ws;
    unsigned short* Xb    = (unsigned short*)(ws);             // 1,048,576 B (dead after proj)
    unsigned short* WT    = (unsigned short*)(ws + 1048576);   //   786,432 B (dead after proj)
    unsigned short* WoutT = (unsigned short*)(ws + 1835008);   //   524,288 B
    unsigned short* Q     = (unsigned short*)(ws + 2359296);   // 8,388,608 B
    unsigned short* Kp    = (unsigned short*)(ws + 10747904);  // 8,388,608 B
    unsigned short* Vt    = (unsigned short*)(ws + 19136512);  // 8,388,608 B
    unsigned short* AsumB = (unsigned short*)(ws + 35913728);  // 16,777,216 B
    _Float16*       Opart = (_Float16*)(ws + 52690944);        // 16,777,216 B (ends 69,468,160)
    float*          Lpart = (float*)(ws);                      // 262,144 B, reuses dead Xb region

    prep_kernel<<<4608, 256, 0, stream>>>(X, Wq, Wk, Wv, Wout, Xb, WT, WoutT);
    adjsum_kernel<<<2048, 256, 0, stream>>>((const float4*)adj, AsumB);
    proj_kernel<<<dim3(NN / 64, BB * HH, 3), 256, 0, stream>>>(Xb, WT, bq, bk, bv, Q, Kp, Vt);
    attn_kernel<<<dim3(128, HH), 256, 0, stream>>>(Q, Kp, Vt, AsumB, Opart, Lpart);
    out_kernel<<<dim3((BB * NN) / 32, OUTD / 64), 256, 0, stream>>>(Opart, Lpart, WoutT, bout, out);
}

// Round 9
// 309.595 us; speedup vs baseline: 1.0175x; 1.0175x over previous
//
#include <hip/hip_runtime.h>
#include <hip/hip_bf16.h>

#define BB 2
#define NN 2048
#define DD 128
#define HH 8
#define OUTD 256
#define SCALE 0.022097086912079612f  // 1/sqrt(2048)

typedef __bf16 bf16x8 __attribute__((ext_vector_type(8)));
typedef float f32x4 __attribute__((ext_vector_type(4)));
typedef _Float16 f16x4 __attribute__((ext_vector_type(4)));

__device__ __forceinline__ unsigned short f2bf(float f) {
    union { float f; unsigned int u; } v; v.f = f;
    unsigned int r = (v.u + 0x7FFFu + ((v.u >> 16) & 1u)) >> 16;
    return (unsigned short)r;
}
__device__ __forceinline__ float bf2f(unsigned short s) {
    union { unsigned int u; float f; } v; v.u = ((unsigned int)s) << 16;
    return v.f;
}
// async global->LDS, 16 B per lane; lds dst = wave-uniform base + lane*16
__device__ __forceinline__ void gl_lds16(const unsigned short* g, unsigned short* l) {
    __builtin_amdgcn_global_load_lds(
        (const __attribute__((address_space(1))) unsigned int*)g,
        (__attribute__((address_space(3))) unsigned int*)l,
        16, 0, 0);
}

// ---------------- prep: bf16 casts + weight transposes ----------------
__global__ void prep_kernel(const float* __restrict__ X,
                            const float* __restrict__ Wq,
                            const float* __restrict__ Wk,
                            const float* __restrict__ Wv,
                            const float* __restrict__ Wout,
                            unsigned short* __restrict__ Xb,     // [B][N][D]
                            unsigned short* __restrict__ WT,     // [3][H][e][d]
                            unsigned short* __restrict__ WoutT)  // [OUT][H*D]
{
    const int NX  = BB * NN * DD;        // 524288
    const int NW  = 3 * HH * DD * DD;    // 393216
    const int NWO = (HH * DD) * OUTD;    // 262144
    int idx = blockIdx.x * blockDim.x + threadIdx.x;
    if (idx < NX) {
        Xb[idx] = f2bf(X[idx]);
    } else if (idx < NX + NW) {
        int i = idx - NX;
        int mat = i / (HH * DD * DD);
        int r   = i % (HH * DD * DD);
        int h = r / (DD * DD);
        int j = r % (DD * DD);
        int e = j / DD;
        int d = j % DD;
        const float* Wm = (mat == 0) ? Wq : ((mat == 1) ? Wk : Wv);
        WT[i] = f2bf(Wm[h * DD * DD + d * DD + e]);
    } else if (idx < NX + NW + NWO) {
        int i = idx - NX - NW;
        int o = i / (HH * DD);
        int k = i % (HH * DD);
        WoutT[i] = f2bf(Wout[k * OUTD + o]);
    }
}

// ---------------- adjsum: nodeadj.sum(-1) -> bf16 ----------------
__global__ void adjsum_kernel(const float4* __restrict__ adj, unsigned short* __restrict__ s) {
    int idx = blockIdx.x * blockDim.x + threadIdx.x;  // B*N*N threads
    float4 a = adj[idx];
    s[idx] = f2bf((a.x + a.y) + (a.z + a.w));
}

// ---------------- projections q/k/v ----------------
// grid (N/64, B*H, 3); block 256. mat: 0=Q, 1=K, 2=V(transposed output via LDS)
__global__ __launch_bounds__(256) void proj_kernel(
    const unsigned short* __restrict__ Xb,
    const unsigned short* __restrict__ WT,
    const float* __restrict__ bq, const float* __restrict__ bk, const float* __restrict__ bv,
    unsigned short* __restrict__ Qo, unsigned short* __restrict__ Ko,
    unsigned short* __restrict__ Vt)
{
    const int mat = blockIdx.z;
    const int bh  = blockIdx.y;
    const int b = bh >> 3, h = bh & 7;
    const int n0 = blockIdx.x * 64;
    const int tid = threadIdx.x;
    const int lane = tid & 63, wv = tid >> 6;
    const int m = lane & 15, quad = lane >> 4;

    __shared__ unsigned short Wlds[128 * 136];  // [e][d], pad 136; reused for V transpose

    const unsigned short* Wg = WT + ((size_t)mat * HH + h) * (DD * DD);
    #pragma unroll
    for (int i = tid; i < 128 * 16; i += 256) {
        int r = i >> 4, c = i & 15;
        *(uint4*)&Wlds[r * 136 + c * 8] = *(const uint4*)(Wg + r * 128 + c * 8);
    }

    const int row = n0 + wv * 16 + m;
    const unsigned short* Xr = Xb + ((size_t)b * NN + row) * DD;
    bf16x8 af[4];
    #pragma unroll
    for (int kc = 0; kc < 4; ++kc)
        af[kc] = *(const bf16x8*)(Xr + kc * 32 + quad * 8);

    __syncthreads();

    f32x4 acc[8];
    #pragma unroll
    for (int et = 0; et < 8; ++et) acc[et] = (f32x4){0.f, 0.f, 0.f, 0.f};

    #pragma unroll
    for (int kc = 0; kc < 4; ++kc) {
        #pragma unroll
        for (int et = 0; et < 8; ++et) {
            bf16x8 bfrg = *(const bf16x8*)&Wlds[(et * 16 + m) * 136 + kc * 32 + quad * 8];
            acc[et] = __builtin_amdgcn_mfma_f32_16x16x32_bf16(af[kc], bfrg, acc[et], 0, 0, 0);
        }
    }

    const float* bias = (mat == 0) ? bq : ((mat == 1) ? bk : bv);
    if (mat != 2) {
        #pragma unroll
        for (int et = 0; et < 8; ++et) {
            int e = et * 16 + m;
            float bb = bias[h * DD + e];
            #pragma unroll
            for (int reg = 0; reg < 4; ++reg) {
                int r = n0 + wv * 16 + quad * 4 + reg;
                unsigned short v16 = f2bf(acc[et][reg] + bb);
                if (mat == 0) Qo[((size_t)bh * NN + r) * DD + e] = v16;
                else          Ko[((size_t)bh * NN + r) * DD + e] = v16;
            }
        }
    } else {
        // V: transpose through LDS -> coalesced uint4 stores to Vt[bh][e][n]
        __syncthreads();  // everyone done with Wlds MFMA reads
        #pragma unroll
        for (int et = 0; et < 8; ++et) {
            int e = et * 16 + m;
            float bb = bias[h * DD + e];
            #pragma unroll
            for (int reg = 0; reg < 4; ++reg)
                Wlds[(wv * 16 + quad * 4 + reg) * 136 + e] = f2bf(acc[et][reg] + bb);
        }
        __syncthreads();
        const int e = tid >> 1, nh = tid & 1;
        #pragma unroll
        for (int j = 0; j < 4; ++j) {
            unsigned short tmp[8];
            #pragma unroll
            for (int kk = 0; kk < 8; ++kk)
                tmp[kk] = Wlds[(nh * 32 + j * 8 + kk) * 136 + e];
            *(uint4*)(Vt + ((size_t)bh * DD + e) * NN + n0 + nh * 32 + j * 8) = *(uint4*)tmp;
        }
    }
}

// ---------------- flash attention, split-K x2, async LDS staging ----------------
// grid (128, 8): x = ((b*32 + qt)*2 + ks), y = h  (h-siblings share XCD: dId=128==0 mod 8)
// block 256 = 4 waves x 16 q-rows. TK=32, double-buffered K/V via global_load_lds,
// XOR-swizzled LDS layout (no padding -> glb_load_lds compatible, conflict-free reads).
__global__ __launch_bounds__(256, 4) void attn_kernel(
    const unsigned short* __restrict__ Q,
    const unsigned short* __restrict__ K,
    const unsigned short* __restrict__ Vt,
    const unsigned short* __restrict__ adjs,   // bf16 [B][N][N]
    _Float16* __restrict__ Opart,              // [2][BH][N][D] fp16 partials
    float* __restrict__ Lpart)                 // [2][BH][N] fp32 partial row-sums
{
    const int x = blockIdx.x;
    const int h = blockIdx.y;
    const int ks = x & 1, qt = (x >> 1) & 31, b = x >> 6;
    const int bh = b * HH + h;
    const int q0 = qt * 64;
    const int kstart = ks * 1024;
    const int tid = threadIdx.x;
    const int lane = tid & 63, wv = tid >> 6;
    const int m = lane & 15, quad = lane >> 4;

    __shared__ unsigned short Kb[2][32 * 128];   // [key][d] swizzled, 8 KB each
    __shared__ unsigned short Vb[2][128 * 32];   // [d][key] swizzled, 8 KB each
    __shared__ unsigned short Plds[4][16 * 40];  // per-wave P, pad 40 -> 5 KB
    // total 37.9 KB -> 4 blocks/CU

    const unsigned short* Kbase = K + (size_t)bh * NN * DD;
    const unsigned short* Vbase = Vt + (size_t)bh * DD * NN;

    // Q fragments (register-resident for whole kernel)
    const int qrow = q0 + wv * 16 + m;
    const unsigned short* Qr = Q + ((size_t)bh * NN + qrow) * DD;
    bf16x8 qf[4];
    #pragma unroll
    for (int kc = 0; kc < 4; ++kc)
        qf[kc] = *(const bf16x8*)(Qr + kc * 32 + quad * 8);

    f32x4 o[8];
    #pragma unroll
    for (int dt = 0; dt < 8; ++dt) o[dt] = (f32x4){0.f, 0.f, 0.f, 0.f};
    float li[4] = {0.f, 0.f, 0.f, 0.f};

    const unsigned short* Abase = adjs + ((size_t)b * NN + q0 + wv * 16 + quad * 4) * NN;

    // staging lane decomposition
    const int kr4 = lane >> 4, kc16 = lane & 15;  // K: 4 rows x 16 chunks / instr
    const int vr16 = lane >> 2, vc4 = lane & 3;   // V: 16 rows x 4 chunks / instr

    // each wave stages K-instrs {2w,2w+1} (rows 8w..8w+7) and V-instrs {2w,2w+1} (d rows 32w..32w+31)
    #define STAGE(buf, kbase_)                                                              \
        {                                                                                   \
            _Pragma("unroll")                                                               \
            for (int j2 = 0; j2 < 2; ++j2) {                                                \
                const int j = wv * 2 + j2;                                                  \
                const int krow = j * 4 + kr4;                                               \
                gl_lds16(Kbase + (size_t)((kbase_) + krow) * DD + ((kc16 ^ (krow & 15)) * 8),\
                         &Kb[buf][j * 512]);                                                \
                const int vrow = j * 16 + vr16;                                             \
                gl_lds16(Vbase + (size_t)vrow * NN + (kbase_) + ((vc4 ^ ((vr16 >> 1) & 3)) * 8),\
                         &Vb[buf][j * 512]);                                                \
            }                                                                               \
        }

    STAGE(0, kstart);
    __syncthreads();   // vmcnt drain -> tile 0 ready

    for (int kt = 0; kt < 32; ++kt) {
        const int cb = kt & 1, nb = cb ^ 1;
        const int k0 = kstart + kt * 32;

        // adj (bf16) for current tile, per-lane scalar loads (consumed after QK)
        float areg[2][4];
        #pragma unroll
        for (int nt = 0; nt < 2; ++nt)
            #pragma unroll
            for (int reg = 0; reg < 4; ++reg)
                areg[nt][reg] = bf2f(Abase[(size_t)reg * NN + k0 + nt * 16 + m]) * SCALE;

        // async-stage next tile (no wait here; barrier at loop end drains)
        if (kt + 1 < 32) STAGE(nb, k0 + 32);

        // QK^T : 8 MFMA
        f32x4 s[2];
        s[0] = (f32x4){0.f, 0.f, 0.f, 0.f};
        s[1] = (f32x4){0.f, 0.f, 0.f, 0.f};
        #pragma unroll
        for (int kc = 0; kc < 4; ++kc) {
            #pragma unroll
            for (int nt = 0; nt < 2; ++nt) {
                bf16x8 kf = *(const bf16x8*)&Kb[cb][(nt * 16 + m) * 128 + (((kc * 4 + quad) ^ m) * 8)];
                s[nt] = __builtin_amdgcn_mfma_f32_16x16x32_bf16(qf[kc], kf, s[nt], 0, 0, 0);
            }
        }

        // p = exp(s*scale*adj)  (no max subtraction: |s*a| < ~1)
        #pragma unroll
        for (int nt = 0; nt < 2; ++nt) {
            #pragma unroll
            for (int reg = 0; reg < 4; ++reg) {
                float p = __expf(s[nt][reg] * areg[nt][reg]);
                li[reg] += p;
                Plds[wv][(quad * 4 + reg) * 40 + nt * 16 + m] = f2bf(p);
            }
        }

        // P x V : 8 MFMA (K=32 covers full tile)
        bf16x8 pf = *(const bf16x8*)&Plds[wv][m * 40 + quad * 8];
        #pragma unroll
        for (int dt = 0; dt < 8; ++dt) {
            bf16x8 vf = *(const bf16x8*)&Vb[cb][(dt * 16 + m) * 32 + ((quad ^ ((m >> 1) & 3)) * 8)];
            o[dt] = __builtin_amdgcn_mfma_f32_16x16x32_bf16(pf, vf, o[dt], 0, 0, 0);
        }

        __syncthreads();  // readers done with cb; stage(nb) drained (vmcnt0 at barrier)
    }
    #undef STAGE

    // partial row-sums: reduce li across the 16 lanes of each row group
    #pragma unroll
    for (int reg = 0; reg < 4; ++reg) {
        float t = li[reg];
        t += __shfl_xor(t, 1);
        t += __shfl_xor(t, 2);
        t += __shfl_xor(t, 4);
        t += __shfl_xor(t, 8);
        li[reg] = t;
    }
    const int rbase = q0 + wv * 16 + quad * 4;
    if (m == 0) {
        #pragma unroll
        for (int reg = 0; reg < 4; ++reg)
            Lpart[((size_t)ks * (BB * HH) + bh) * NN + rbase + reg] = li[reg];
    }
    // unnormalized partial O in fp16
    #pragma unroll
    for (int reg = 0; reg < 4; ++reg) {
        const size_t obase = (((size_t)ks * (BB * HH) + bh) * NN + rbase + reg) * DD;
        #pragma unroll
        for (int dt = 0; dt < 8; ++dt)
            Opart[obase + dt * 16 + m] = (_Float16)o[dt][reg];
    }
}

// ---------------- combine split-K partials -> Ocat bf16 ----------------
__global__ void combine_kernel(const _Float16* __restrict__ Op,
                               const float* __restrict__ Lp,
                               unsigned short* __restrict__ Ocat)
{
    const int SPLIT_OFF = BB * HH * NN * DD;   // 4,194,304
    int t = blockIdx.x * blockDim.x + threadIdx.x;   // 1,048,576 threads
    int e0 = t * 4;
    int row = e0 >> 7;                         // bh*N + n
    float l = 1.0f / (Lp[row] + Lp[row + BB * HH * NN]);
    f16x4 a = *(const f16x4*)(Op + e0);
    f16x4 c = *(const f16x4*)(Op + SPLIT_OFF + e0);
    int bh = row >> 11, n = row & (NN - 1);
    int b = bh >> 3, h = bh & 7;
    size_t obase = ((size_t)(b * NN + n)) * (HH * DD) + h * DD + (e0 & (DD - 1));
    unsigned short u[4];
    #pragma unroll
    for (int i = 0; i < 4; ++i)
        u[i] = f2bf(((float)a[i] + (float)c[i]) * l);
    *(ushort4*)(Ocat + obase) = *(ushort4*)u;
}

// ---------------- output projection: [4096 x 1024] @ [1024 x 256] + bout ----------------
__global__ __launch_bounds__(256) void out_kernel(
    const unsigned short* __restrict__ Ocat,
    const unsigned short* __restrict__ WoutT,   // [OUT][HD]
    const float* __restrict__ bout,
    float* __restrict__ out)
{
    const int m0 = blockIdx.x * 64;
    const int c0 = blockIdx.y * 64;
    const int tid = threadIdx.x;
    const int lane = tid & 63, wv = tid >> 6;
    const int m = lane & 15, quad = lane >> 4;

    __shared__ unsigned short Wlds[64 * 136];

    f32x4 acc[4];
    #pragma unroll
    for (int nt = 0; nt < 4; ++nt) acc[nt] = (f32x4){0.f, 0.f, 0.f, 0.f};

    const unsigned short* Orow = Ocat + (size_t)(m0 + wv * 16 + m) * (HH * DD);

    for (int kc = 0; kc < 8; ++kc) {
        #pragma unroll
        for (int i = tid; i < 64 * 16; i += 256) {
            int r = i >> 4, c = i & 15;
            *(uint4*)&Wlds[r * 136 + c * 8] =
                *(const uint4*)(WoutT + (size_t)(c0 + r) * (HH * DD) + kc * 128 + c * 8);
        }
        __syncthreads();
        #pragma unroll
        for (int j = 0; j < 4; ++j) {
            bf16x8 afr = *(const bf16x8*)(Orow + kc * 128 + j * 32 + quad * 8);
            #pragma unroll
            for (int nt = 0; nt < 4; ++nt) {
                bf16x8 bfr = *(const bf16x8*)&Wlds[(nt * 16 + m) * 136 + j * 32 + quad * 8];
                acc[nt] = __builtin_amdgcn_mfma_f32_16x16x32_bf16(afr, bfr, acc[nt], 0, 0, 0);
            }
        }
        __syncthreads();
    }

    #pragma unroll
    for (int nt = 0; nt < 4; ++nt) {
        int oc = c0 + nt * 16 + m;
        float bb = bout[oc];
        #pragma unroll
        for (int reg = 0; reg < 4; ++reg) {
            int r = m0 + wv * 16 + quad * 4 + reg;
            out[(size_t)r * OUTD + oc] = acc[nt][reg] + bb;
        }
    }
}

extern "C" void kernel_launch(void* const* d_in, const int* in_sizes, int n_in,
                              void* d_out, int out_size, void* d_ws, size_t ws_size,
                              hipStream_t stream)
{
    const float* X    = (const float*)d_in[0];
    const float* adj  = (const float*)d_in[1];
    const float* Wq   = (const float*)d_in[2];
    const float* bq   = (const float*)d_in[3];
    const float* Wk   = (const float*)d_in[4];
    const float* bk   = (const float*)d_in[5];
    const float* Wv   = (const float*)d_in[6];
    const float* bv   = (const float*)d_in[7];
    const float* Wout = (const float*)d_in[8];
    const float* bout = (const float*)d_in[9];
    float* out = (float*)d_out;

    char* ws = (char*)d_ws;
    unsigned short* Xb    = (unsigned short*)(ws);             // 1,048,576 B (dead after proj)
    unsigned short* WT    = (unsigned short*)(ws + 1048576);   //   786,432 B (dead after proj)
    unsigned short* WoutT = (unsigned short*)(ws + 1835008);   //   524,288 B
    unsigned short* Q     = (unsigned short*)(ws + 2359296);   // 8,388,608 B
    unsigned short* Kp    = (unsigned short*)(ws + 10747904);  // 8,388,608 B
    unsigned short* Vt    = (unsigned short*)(ws + 19136512);  // 8,388,608 B
    unsigned short* Ocat  = (unsigned short*)(ws + 27525120);  // 8,388,608 B
    unsigned short* AsumB = (unsigned short*)(ws + 35913728);  // 16,777,216 B
    _Float16*       Opart = (_Float16*)(ws + 52690944);        // 16,777,216 B (ends 69,468,160)
    float*          Lpart = (float*)(ws);                      // 262,144 B, reuses dead Xb region

    prep_kernel<<<4608, 256, 0, stream>>>(X, Wq, Wk, Wv, Wout, Xb, WT, WoutT);
    adjsum_kernel<<<(BB * NN * NN) / 256, 256, 0, stream>>>((const float4*)adj, AsumB);
    proj_kernel<<<dim3(NN / 64, BB * HH, 3), 256, 0, stream>>>(Xb, WT, bq, bk, bv, Q, Kp, Vt);
    attn_kernel<<<dim3(128, HH), 256, 0, stream>>>(Q, Kp, Vt, AsumB, Opart, Lpart);
    combine_kernel<<<(BB * HH * NN * DD / 4) / 256, 256, 0, stream>>>(Opart, Lpart, Ocat);
    out_kernel<<<dim3((BB * NN) / 64, OUTD / 64), 256, 0, stream>>>(Ocat, WoutT, bout, out);
}